// Round 12
// baseline (170.700 us; speedup 1.0000x reference)
//
#include <hip/hip_runtime.h>

typedef __attribute__((ext_vector_type(8))) short bf16x8;
typedef __attribute__((ext_vector_type(4))) short bf16x4;
typedef __attribute__((ext_vector_type(4))) float f32x4;
typedef __attribute__((ext_vector_type(4))) float floatx4;

__device__ __forceinline__ unsigned short f2bf(float f) {
    unsigned int u = __float_as_uint(f);
    u += 0x7fffu + ((u >> 16) & 1u);   // round-to-nearest-even
    return (unsigned short)(u >> 16);
}
__device__ __forceinline__ float bf2f_s(short h) {
    return __uint_as_float(((unsigned int)(unsigned short)h) << 16);
}
__device__ __forceinline__ bf16x4 cvt4(f32x4 v) {
    union { unsigned int u[2]; bf16x4 x; } r;
    asm("v_cvt_pk_bf16_f32 %0, %1, %2" : "=v"(r.u[0]) : "v"(v[0]), "v"(v[1]));
    asm("v_cvt_pk_bf16_f32 %0, %1, %2" : "=v"(r.u[1]) : "v"(v[2]), "v"(v[3]));
    return r.x;
}

// ---------------- kernel 0: weight conversion to bf16 ----------------
// Wkvb[256][1024]: rows 0-127 = Wk, 128-255 = Wv.  Wob[1024][128] = Wo.
__global__ void k_convert(const float* __restrict__ Wk, const float* __restrict__ Wv,
                          const float* __restrict__ Wo,
                          unsigned short* __restrict__ Wkvb, unsigned short* __restrict__ Wob) {
    int i = (blockIdx.x * blockDim.x + threadIdx.x) * 4;
    if (i < 131072) {
        floatx4 a = *reinterpret_cast<const floatx4*>(Wk + i);
        floatx4 b = *reinterpret_cast<const floatx4*>(Wv + i);
        floatx4 c = *reinterpret_cast<const floatx4*>(Wo + i);
        *reinterpret_cast<bf16x4*>(Wkvb + i)          = cvt4(a);
        *reinterpret_cast<bf16x4*>(Wkvb + 131072 + i) = cvt4(b);
        *reinterpret_cast<bf16x4*>(Wob + i)           = cvt4(c);
    }
}

// ---------------- fused kernel: keys/vals GEMM + attention, 1 batch per block ----------------
// Phase 1 (GEMM): byte-minimal (A read once, B bf16 once per block), BK=64, 16 steps,
// 2-step register lookahead, raw s_barrier + lgkmcnt-only flush (vmcnt never drained).
// Phase 2: K/V written straight into LDS by the epilogue; attention runs in-block.
__global__ __launch_bounds__(512)
void k_fused(const float* __restrict__ patches,
             const unsigned short* __restrict__ Wkvb,
             const float* __restrict__ patch_pos,
             const float* __restrict__ queries,
             const float* __restrict__ prior,
             const float* __restrict__ temperature,
             float* __restrict__ attn_out,
             unsigned short* __restrict__ att)
{
    // union layout:
    //   phase 1: As[buf] @ buf*29952 (208x72 ushort), Bs[buf] @ 59904 + buf*36864 (256x72)
    //   phase 2: k_s[196][136] @ 0, v_s[196][128] @ 53312, q_s[52][128] @ 103488,
    //            l_s[52][196] (f32) @ 116800   (total 157568 B)
    __shared__ char smem[157568];

    const int tid  = threadIdx.x;
    const int lane = tid & 63;
    const int w    = tid >> 6;       // 0..7 : 32-col N slice (phase 1) / wave id (phase 2)
    const int l15  = lane & 15;
    const int lg   = lane >> 4;      // 0..3
    const int b    = blockIdx.x;     // batch
    const float* abase = patches + (size_t)b * 196 * 1024;

    // B staging: 2 threads/row, 64B each
    const int brow = tid >> 1;       // 0..255
    const int bh   = tid & 1;
    const unsigned short* bgp = Wkvb + (size_t)brow * 1024 + bh * 32;

    f32x4 acc[13][2];
    #pragma unroll
    for (int i = 0; i < 13; ++i) {
        acc[i][0] = (f32x4){0.f, 0.f, 0.f, 0.f};
        acc[i][1] = (f32x4){0.f, 0.f, 0.f, 0.f};
    }

    f32x4  a0H[7], a1H[7];
    bf16x8 b0H[4], b1H[4];

#define ISSUE(AH, BH, T)                                                          \
    do { const int ko_ = (T) * 64;                                                \
        _Pragma("unroll")                                                         \
        for (int i_ = 0; i_ < 6; ++i_) {                                          \
            int g_ = tid + i_ * 512; int r_ = g_ >> 4, gc_ = g_ & 15;             \
            AH[i_] = *reinterpret_cast<const f32x4*>(abase + (size_t)r_ * 1024 + ko_ + gc_ * 4); \
        }                                                                         \
        if (tid < 64) { int g_ = 3072 + tid; int r_ = g_ >> 4, gc_ = g_ & 15;     \
            AH[6] = *reinterpret_cast<const f32x4*>(abase + (size_t)r_ * 1024 + ko_ + gc_ * 4); } \
        _Pragma("unroll")                                                         \
        for (int j_ = 0; j_ < 4; ++j_)                                            \
            BH[j_] = *reinterpret_cast<const bf16x8*>(bgp + ko_ + j_ * 8);        \
    } while (0)

#define STORE(AH, BH, BUF)                                                        \
    do { unsigned short* As_ = (unsigned short*)(smem + (BUF) * 29952);           \
         unsigned short* Bs_ = (unsigned short*)(smem + 59904 + (BUF) * 36864);   \
        _Pragma("unroll")                                                         \
        for (int i_ = 0; i_ < 6; ++i_) {                                          \
            int g_ = tid + i_ * 512; int r_ = g_ >> 4, gc_ = g_ & 15;             \
            *reinterpret_cast<bf16x4*>(As_ + r_ * 72 + gc_ * 4) = cvt4(AH[i_]);   \
        }                                                                         \
        if (tid < 64) { int g_ = 3072 + tid; int r_ = g_ >> 4, gc_ = g_ & 15;     \
            *reinterpret_cast<bf16x4*>(As_ + r_ * 72 + gc_ * 4) = cvt4(AH[6]); }  \
        _Pragma("unroll")                                                         \
        for (int j_ = 0; j_ < 4; ++j_)                                            \
            *reinterpret_cast<bf16x8*>(Bs_ + brow * 72 + bh * 32 + j_ * 8) = BH[j_]; \
    } while (0)

#define COMPUTE(BUF)                                                              \
    do { const unsigned short* As_ = (const unsigned short*)(smem + (BUF) * 29952); \
         const unsigned short* Bs_ = (const unsigned short*)(smem + 59904 + (BUF) * 36864); \
        _Pragma("unroll")                                                         \
        for (int kk_ = 0; kk_ < 2; ++kk_) {                                       \
            bf16x8 bf0 = *reinterpret_cast<const bf16x8*>(Bs_ + (w * 32 + l15) * 72 + kk_ * 32 + lg * 8);      \
            bf16x8 bf1 = *reinterpret_cast<const bf16x8*>(Bs_ + (w * 32 + 16 + l15) * 72 + kk_ * 32 + lg * 8); \
            _Pragma("unroll")                                                     \
            for (int mf_ = 0; mf_ < 13; ++mf_) {                                  \
                bf16x8 af = *reinterpret_cast<const bf16x8*>(As_ + (mf_ * 16 + l15) * 72 + kk_ * 32 + lg * 8); \
                acc[mf_][0] = __builtin_amdgcn_mfma_f32_16x16x32_bf16(af, bf0, acc[mf_][0], 0, 0, 0); \
                acc[mf_][1] = __builtin_amdgcn_mfma_f32_16x16x32_bf16(af, bf1, acc[mf_][1], 0, 0, 0); \
            }                                                                     \
        }                                                                         \
    } while (0)

#define FENCE                                                                     \
    do { __builtin_amdgcn_sched_barrier(0);                                       \
         asm volatile("s_waitcnt lgkmcnt(0)" ::: "memory");                       \
         __builtin_amdgcn_s_barrier();                                            \
         __builtin_amdgcn_sched_barrier(0); } while (0)

    // prologue: tile0 staged; tile1 in flight
    ISSUE(a0H, b0H, 0);
    STORE(a0H, b0H, 0);
    ISSUE(a1H, b1H, 1);
    FENCE;

    for (int tb = 0; tb < 16; tb += 2) {
        // even step tb: compute buf0 (tile tb); issue tile tb+2; land tile tb+1
        if (tb + 2 < 16) ISSUE(a0H, b0H, tb + 2);
        COMPUTE(0);
        STORE(a1H, b1H, 1);
        FENCE;
        // odd step tb+1: compute buf1 (tile tb+1); issue tile tb+3; land tile tb+2
        if (tb + 3 < 16) ISSUE(a1H, b1H, tb + 3);
        COMPUTE(1);
        if (tb + 1 < 15) STORE(a0H, b0H, 0);
        FENCE;
    }
#undef ISSUE
#undef STORE
#undef COMPUTE
#undef FENCE

    // ---- phase 2 layout ----
    unsigned short (*k_s)[136] = (unsigned short (*)[136])(smem);
    unsigned short (*v_s)[128] = (unsigned short (*)[128])(smem + 53312);
    unsigned short (*q_s)[128] = (unsigned short (*)[128])(smem + 103488);
    float          (*l_s)[196] = (float (*)[196])(smem + 116800);

    // epilogue: acc -> K/V in LDS (C/D layout: col=lane&15 (n), row=(lane>>4)*4+i)
    #pragma unroll
    for (int mf = 0; mf < 13; ++mf) {
        #pragma unroll
        for (int i = 0; i < 4; ++i) {
            int ml = mf * 16 + lg * 4 + i;           // local row = patch index kp
            if (ml < 196) {
                #pragma unroll
                for (int nf = 0; nf < 2; ++nf) {
                    int n = w * 32 + nf * 16 + l15;
                    float v = acc[mf][nf][i];
                    if (n < 128) k_s[ml][n] = f2bf(v + patch_pos[ml * 128 + n]);
                    else         v_s[ml][n - 128] = f2bf(v);
                }
            }
        }
    }
    // stage Q (f32 -> bf16)
    for (int idx = tid; idx < 1664; idx += 512) {
        int row = idx >> 5;
        int c   = (idx & 31) * 4;
        f32x4 qv = *reinterpret_cast<const f32x4*>(queries + row * 128 + c);
        *reinterpret_cast<bf16x4*>(&q_s[row][c]) = cvt4(qv);
    }
    __syncthreads();

    const float inv_temp  = 1.0f / (log1pf(expf(temperature[0])) + 0.5f);
    const float inv_scale = 0.08838834764831845f;

    // logits
    for (int task = tid; task < 3328; task += 512) {
        int q  = task >> 6;          // wave-uniform
        int kg = task & 63;
        if (kg < 49) {
            float dot0 = 0.f, dot1 = 0.f, dot2 = 0.f, dot3 = 0.f;
            #pragma unroll 4
            for (int c = 0; c < 128; c += 8) {
                bf16x8 qv = *reinterpret_cast<const bf16x8*>(&q_s[q][c]);
                float qf[8];
                #pragma unroll
                for (int e = 0; e < 8; ++e) qf[e] = bf2f_s(qv[e]);
                bf16x8 k0v = *reinterpret_cast<const bf16x8*>(&k_s[kg][c]);
                bf16x8 k1v = *reinterpret_cast<const bf16x8*>(&k_s[kg + 49][c]);
                bf16x8 k2v = *reinterpret_cast<const bf16x8*>(&k_s[kg + 98][c]);
                bf16x8 k3v = *reinterpret_cast<const bf16x8*>(&k_s[kg + 147][c]);
                #pragma unroll
                for (int e = 0; e < 8; ++e) {
                    dot0 += qf[e] * bf2f_s(k0v[e]);
                    dot1 += qf[e] * bf2f_s(k1v[e]);
                    dot2 += qf[e] * bf2f_s(k2v[e]);
                    dot3 += qf[e] * bf2f_s(k3v[e]);
                }
            }
            int k;
            k = kg;       l_s[q][k] = (dot0 * inv_scale + prior[q * 196 + k]) * inv_temp;
            k = kg + 49;  l_s[q][k] = (dot1 * inv_scale + prior[q * 196 + k]) * inv_temp;
            k = kg + 98;  l_s[q][k] = (dot2 * inv_scale + prior[q * 196 + k]) * inv_temp;
            k = kg + 147; l_s[q][k] = (dot3 * inv_scale + prior[q * 196 + k]) * inv_temp;
        }
    }
    __syncthreads();

    // softmax: one wave per q row (8 waves)
    for (int q = w; q < 52; q += 8) {
        float x0 = l_s[q][lane];
        float x1 = l_s[q][lane + 64];
        float x2 = l_s[q][lane + 128];
        float x3 = (lane < 4) ? l_s[q][lane + 192] : -1e30f;
        float m = fmaxf(fmaxf(x0, x1), fmaxf(x2, x3));
        #pragma unroll
        for (int off = 32; off > 0; off >>= 1) m = fmaxf(m, __shfl_xor(m, off));
        float e0 = expf(x0 - m), e1 = expf(x1 - m), e2 = expf(x2 - m);
        float e3 = (lane < 4) ? expf(x3 - m) : 0.0f;
        float s = e0 + e1 + e2 + e3;
        #pragma unroll
        for (int off = 32; off > 0; off >>= 1) s += __shfl_xor(s, off);
        float inv = 1.0f / s;
        float* po = attn_out + ((size_t)b * 52 + q) * 196;
        float a0 = e0 * inv, a1 = e1 * inv, a2 = e2 * inv;
        l_s[q][lane]       = a0;  po[lane]       = a0;
        l_s[q][lane + 64]  = a1;  po[lane + 64]  = a1;
        l_s[q][lane + 128] = a2;  po[lane + 128] = a2;
        if (lane < 4) { float a3 = e3 * inv; l_s[q][lane + 192] = a3; po[lane + 192] = a3; }
    }
    __syncthreads();

    // attended -> att (bf16)
    for (int task = tid; task < 832; task += 512) {
        int q  = task >> 4;
        int a0 = (task & 15) * 8;
        float accv[8] = {0.f, 0.f, 0.f, 0.f, 0.f, 0.f, 0.f, 0.f};
        for (int k = 0; k < 196; ++k) {
            float wgt = l_s[q][k];
            bf16x8 vv = *reinterpret_cast<const bf16x8*>(&v_s[k][a0]);
            #pragma unroll
            for (int e = 0; e < 8; ++e) accv[e] += wgt * bf2f_s(vv[e]);
        }
        bf16x8 sv;
        #pragma unroll
        for (int e = 0; e < 8; ++e) sv[e] = (short)f2bf(accv[e]);
        *reinterpret_cast<bf16x8*>(att + ((size_t)b * 52 + q) * 128 + a0) = sv;
    }
}

// ---------------- kernel 3: output GEMM ----------------
__global__ __launch_bounds__(512)
void k_out(const unsigned short* __restrict__ att,
           const unsigned short* __restrict__ Wob,
           const float* __restrict__ bo,
           float* __restrict__ out)
{
    __shared__ unsigned short As[64][72];
    __shared__ unsigned short Bs[256][72];

    const int tid  = threadIdx.x;
    const int lane = tid & 63;
    const int wave = tid >> 6;
    const int wm   = wave >> 2;
    const int wn   = wave & 3;
    const int l15  = lane & 15;
    const int lg   = lane >> 4;
    const int row0 = blockIdx.x * 64;
    const int e0   = blockIdx.y * 256;

    f32x4 acc[2][4];
    #pragma unroll
    for (int i = 0; i < 2; ++i)
        #pragma unroll
        for (int j = 0; j < 4; ++j)
            acc[i][j] = (f32x4){0.f, 0.f, 0.f, 0.f};

    for (int ko = 0; ko < 128; ko += 64) {
        {
            int r = tid >> 3;
            int c = (tid & 7) * 8;
            bf16x8 v = *reinterpret_cast<const bf16x8*>(att + (size_t)(row0 + r) * 128 + ko + c);
            *reinterpret_cast<bf16x8*>(&As[r][c]) = v;
        }
        {
            int r = tid >> 3;
            int c = (tid & 7) * 8;
            #pragma unroll
            for (int it = 0; it < 4; ++it) {
                bf16x8 v = *reinterpret_cast<const bf16x8*>(Wob + (size_t)(e0 + it * 64 + r) * 128 + ko + c);
                *reinterpret_cast<bf16x8*>(&Bs[it * 64 + r][c]) = v;
            }
        }
        __syncthreads();
        #pragma unroll
        for (int kk = 0; kk < 2; ++kk) {
            bf16x8 af[2], bfr[4];
            #pragma unroll
            for (int mi = 0; mi < 2; ++mi)
                af[mi] = *reinterpret_cast<const bf16x8*>(&As[wm * 32 + mi * 16 + l15][kk * 32 + lg * 8]);
            #pragma unroll
            for (int ni = 0; ni < 4; ++ni)
                bfr[ni] = *reinterpret_cast<const bf16x8*>(&Bs[wn * 64 + ni * 16 + l15][kk * 32 + lg * 8]);
            #pragma unroll
            for (int mi = 0; mi < 2; ++mi)
                #pragma unroll
                for (int ni = 0; ni < 4; ++ni)
                    acc[mi][ni] = __builtin_amdgcn_mfma_f32_16x16x32_bf16(af[mi], bfr[ni], acc[mi][ni], 0, 0, 0);
        }
        __syncthreads();
    }
    #pragma unroll
    for (int mi = 0; mi < 2; ++mi) {
        #pragma unroll
        for (int i = 0; i < 4; ++i) {
            int m = row0 + wm * 32 + mi * 16 + lg * 4 + i;
            #pragma unroll
            for (int ni = 0; ni < 4; ++ni) {
                int e = e0 + wn * 64 + ni * 16 + l15;
                out[(size_t)m * 1024 + e] = acc[mi][ni][i] + bo[e];
            }
        }
    }
}

extern "C" void kernel_launch(void* const* d_in, const int* in_sizes, int n_in,
                              void* d_out, int out_size, void* d_ws, size_t ws_size,
                              hipStream_t stream)
{
    const float* patches     = (const float*)d_in[0];   // [256][196][1024]
    const float* queries     = (const float*)d_in[1];   // [52][128]
    const float* Wk          = (const float*)d_in[2];   // [128][1024]
    const float* Wv          = (const float*)d_in[3];   // [128][1024]
    const float* Wo          = (const float*)d_in[4];   // [1024][128]
    const float* bo          = (const float*)d_in[5];   // [1024]
    const float* patch_pos   = (const float*)d_in[6];   // [196][128]
    const float* temperature = (const float*)d_in[7];   // [1]
    const float* prior       = (const float*)d_in[8];   // [52][196]

    float* out      = (float*)d_out;                    // [256*52][1024]
    float* attn_out = out + (size_t)256 * 52 * 1024;    // [256*52][196]

    unsigned short* Wkvb = (unsigned short*)d_ws;              // 256*1024
    unsigned short* Wob  = Wkvb + 262144;                      // 1024*128
    unsigned short* att  = Wob + 131072;                       // 13312*128

    k_convert<<<128, 256, 0, stream>>>(Wk, Wv, Wo, Wkvb, Wob);
    k_fused  <<<256, 512, 0, stream>>>(patches, Wkvb, patch_pos, queries, prior,
                                       temperature, attn_out, att);
    k_out    <<<dim3(208, 4), 512, 0, stream>>>(att, Wob, bo, out);
}

// Round 13
// 135.502 us; speedup vs baseline: 1.2598x; 1.2598x over previous
//
#include <hip/hip_runtime.h>

typedef __attribute__((ext_vector_type(8))) short bf16x8;
typedef __attribute__((ext_vector_type(4))) short bf16x4;
typedef __attribute__((ext_vector_type(4))) float f32x4;
typedef __attribute__((ext_vector_type(4))) float floatx4;

__device__ __forceinline__ unsigned short f2bf(float f) {
    unsigned int u = __float_as_uint(f);
    u += 0x7fffu + ((u >> 16) & 1u);   // round-to-nearest-even
    return (unsigned short)(u >> 16);
}
__device__ __forceinline__ float bf2f_s(short h) {
    return __uint_as_float(((unsigned int)(unsigned short)h) << 16);
}
__device__ __forceinline__ bf16x4 cvt4(f32x4 v) {
    union { unsigned int u[2]; bf16x4 x; } r;
    asm("v_cvt_pk_bf16_f32 %0, %1, %2" : "=v"(r.u[0]) : "v"(v[0]), "v"(v[1]));
    asm("v_cvt_pk_bf16_f32 %0, %1, %2" : "=v"(r.u[1]) : "v"(v[2]), "v"(v[3]));
    return r.x;
}

// ---------------- kernel 0: weight conversion to bf16 ----------------
// Wkvb[256][1024]: rows 0-127 = Wk, 128-255 = Wv.  Wob[1024][128] = Wo.
__global__ void k_convert(const float* __restrict__ Wk, const float* __restrict__ Wv,
                          const float* __restrict__ Wo,
                          unsigned short* __restrict__ Wkvb, unsigned short* __restrict__ Wob) {
    int i = (blockIdx.x * blockDim.x + threadIdx.x) * 4;
    if (i < 131072) {
        floatx4 a = *reinterpret_cast<const floatx4*>(Wk + i);
        floatx4 b = *reinterpret_cast<const floatx4*>(Wv + i);
        floatx4 c = *reinterpret_cast<const floatx4*>(Wo + i);
        *reinterpret_cast<bf16x4*>(Wkvb + i)          = cvt4(a);
        *reinterpret_cast<bf16x4*>(Wkvb + 131072 + i) = cvt4(b);
        *reinterpret_cast<bf16x4*>(Wob + i)           = cvt4(c);
    }
}

// ---------------- kernel 1: keys/vals GEMM (byte-minimal + 2-deep counted pipeline) ----------------
// kv[m][n] = sum_e patches[m][e] * Wkvb[n][e]  (+ patch_pos bias for n<128)
// Grid 256 (1 batch per block -> A read once, B bf16 once per block = 333 MB issued total).
// 1024 thr / 16 waves (wave = 196M x 16N, acc[13][1]); BK=32, 32 steps.
// Two register sets: tile t+2 issued at step t, stored at step t+1 (~1.5 steps flight);
// FENCE = lgkmcnt-only flush + raw s_barrier -> vmcnt never drained in the loop.
__global__ __launch_bounds__(1024, 4)
void k_keysvals(const float* __restrict__ patches,
                const unsigned short* __restrict__ Wkvb,
                const float* __restrict__ patch_pos,
                unsigned short* __restrict__ kv)
{
    // per buffer: As 208 rows x 40 ushorts (16640 B) + Bs 256 x 40 (20480 B)
    // buf0: As@0  Bs@16640 ; buf1: As@37120 Bs@53760 ; total 74240 B
    __shared__ char smem[74240];

    const int tid  = threadIdx.x;
    const int lane = tid & 63;
    const int w    = tid >> 6;       // 0..15 : 16-col N slice
    const int l15  = lane & 15;
    const int lg   = lane >> 4;      // 0..3
    const int b    = blockIdx.x;     // batch
    const float* abase = patches + (size_t)b * 196 * 1024;

    // A: 1568 granules/step (196 rows x 8); thread covers g=tid and g=1024+tid (tid<544)
    const int ar0 = tid >> 3,          ac0 = tid & 7;          // granule tid
    const int ar1 = (1024 + tid) >> 3, ac1 = (1024 + tid) & 7; // granule 1024+tid
    // B: 1024 granules/step (256 rows x 4); thread covers g=tid
    const int br = tid >> 2, bc = tid & 3;
    const unsigned short* bgp = Wkvb + (size_t)br * 1024 + bc * 8;

    f32x4  a0A, a0B, a1A, a1B;       // set0/set1 A granules (B-slot cond on tid<544)
    bf16x8 b0H, b1H;                 // set0/set1 B granule

    f32x4 acc[13];
    #pragma unroll
    for (int i = 0; i < 13; ++i) acc[i] = (f32x4){0.f, 0.f, 0.f, 0.f};

#define ISSUE(AA, AB, BH, T)                                                       \
    do { const int ko_ = (T) * 32;                                                 \
        AA = *reinterpret_cast<const f32x4*>(abase + (size_t)ar0 * 1024 + ko_ + ac0 * 4); \
        if (tid < 544)                                                             \
            AB = *reinterpret_cast<const f32x4*>(abase + (size_t)ar1 * 1024 + ko_ + ac1 * 4); \
        BH = *reinterpret_cast<const bf16x8*>(bgp + (T) * 32);                     \
    } while (0)

#define STORE(AA, AB, BH, BUF)                                                     \
    do { unsigned short* As_ = (unsigned short*)(smem + (BUF) * 37120);            \
         unsigned short* Bs_ = (unsigned short*)(smem + (BUF) * 37120 + 16640);    \
        *reinterpret_cast<bf16x4*>(As_ + ar0 * 40 + ac0 * 4) = cvt4(AA);           \
        if (tid < 544)                                                             \
            *reinterpret_cast<bf16x4*>(As_ + ar1 * 40 + ac1 * 4) = cvt4(AB);       \
        *reinterpret_cast<bf16x8*>(Bs_ + br * 40 + bc * 8) = BH;                   \
    } while (0)

#define COMPUTE(BUF)                                                               \
    do { const unsigned short* As_ = (const unsigned short*)(smem + (BUF) * 37120);  \
         const unsigned short* Bs_ = (const unsigned short*)(smem + (BUF) * 37120 + 16640); \
        bf16x8 bf = *reinterpret_cast<const bf16x8*>(Bs_ + (w * 16 + l15) * 40 + lg * 8);  \
        _Pragma("unroll")                                                          \
        for (int mf_ = 0; mf_ < 13; ++mf_) {                                       \
            bf16x8 af = *reinterpret_cast<const bf16x8*>(As_ + (mf_ * 16 + l15) * 40 + lg * 8); \
            acc[mf_] = __builtin_amdgcn_mfma_f32_16x16x32_bf16(af, bf, acc[mf_], 0, 0, 0); \
        }                                                                          \
    } while (0)

#define FENCE                                                                      \
    do { __builtin_amdgcn_sched_barrier(0);                                        \
         asm volatile("s_waitcnt lgkmcnt(0)" ::: "memory");                        \
         __builtin_amdgcn_s_barrier();                                             \
         __builtin_amdgcn_sched_barrier(0); } while (0)

    // prologue: tile0 staged to buf0; tile1 in flight (set1)
    ISSUE(a0A, a0B, b0H, 0);
    STORE(a0A, a0B, b0H, 0);
    ISSUE(a1A, a1B, b1H, 1);
    FENCE;

    for (int tb = 0; tb < 32; tb += 2) {
        // even step T=tb: compute tile T (buf0); store tile T+1 (set1 -> buf1); issue tile T+2 (set0)
        if (tb + 2 < 32) ISSUE(a0A, a0B, b0H, tb + 2);
        COMPUTE(0);
        STORE(a1A, a1B, b1H, 1);
        FENCE;
        // odd step T=tb+1: compute tile T (buf1); store tile T+1 (set0 -> buf0); issue tile T+2 (set1)
        if (tb + 3 < 32) ISSUE(a1A, a1B, b1H, tb + 3);
        COMPUTE(1);
        if (tb + 2 < 32) STORE(a0A, a0B, b0H, 0);
        if (tb + 1 < 31) FENCE;
    }
#undef ISSUE
#undef STORE
#undef COMPUTE
#undef FENCE

    // epilogue: C/D layout col=lane&15 (n), row=(lane>>4)*4+i (m local = kp)
    #pragma unroll
    for (int mf = 0; mf < 13; ++mf) {
        #pragma unroll
        for (int i = 0; i < 4; ++i) {
            int ml = mf * 16 + lg * 4 + i;
            if (ml < 196) {
                int n = w * 16 + l15;
                float v = acc[mf][i];
                if (n < 128) v += patch_pos[ml * 128 + n];
                kv[((size_t)b * 196 + ml) * 256 + n] = f2bf(v);
            }
        }
    }
}

// ---------------- kernel 2: per-batch attention (R10 verbatim) ----------------
__global__ __launch_bounds__(1024)
void k_attn(const unsigned short* __restrict__ kv,
            const float* __restrict__ queries,
            const float* __restrict__ prior,
            const float* __restrict__ temperature,
            float* __restrict__ attn_out,
            unsigned short* __restrict__ att)
{
    __shared__ unsigned short k_s[196][136];
    __shared__ unsigned short v_s[196][128];
    __shared__ unsigned short q_s[52][128];
    __shared__ float          l_s[52][196];

    const int b   = blockIdx.x;
    const int tid = threadIdx.x;
    const size_t base = (size_t)b * 196 * 256;

    for (int idx = tid; idx < 6272; idx += 1024) {
        int row = idx >> 5;
        int c   = (idx & 31) * 8;
        bf16x8 v = *reinterpret_cast<const bf16x8*>(kv + base + row * 256 + c);
        if (c < 128) *reinterpret_cast<bf16x8*>(&k_s[row][c])       = v;
        else         *reinterpret_cast<bf16x8*>(&v_s[row][c - 128]) = v;
    }
    for (int idx = tid; idx < 1664; idx += 1024) {
        int row = idx >> 5;
        int c   = (idx & 31) * 4;
        f32x4 qv = *reinterpret_cast<const f32x4*>(queries + row * 128 + c);
        *reinterpret_cast<bf16x4*>(&q_s[row][c]) = cvt4(qv);
    }
    __syncthreads();

    const float inv_temp  = 1.0f / (log1pf(expf(temperature[0])) + 0.5f);
    const float inv_scale = 0.08838834764831845f;

    for (int task = tid; task < 3328; task += 1024) {
        int q  = task >> 6;
        int kg = task & 63;
        if (kg < 49) {
            float dot0 = 0.f, dot1 = 0.f, dot2 = 0.f, dot3 = 0.f;
            #pragma unroll 4
            for (int c = 0; c < 128; c += 8) {
                bf16x8 qv = *reinterpret_cast<const bf16x8*>(&q_s[q][c]);
                float qf[8];
                #pragma unroll
                for (int e = 0; e < 8; ++e) qf[e] = bf2f_s(qv[e]);
                bf16x8 k0v = *reinterpret_cast<const bf16x8*>(&k_s[kg][c]);
                bf16x8 k1v = *reinterpret_cast<const bf16x8*>(&k_s[kg + 49][c]);
                bf16x8 k2v = *reinterpret_cast<const bf16x8*>(&k_s[kg + 98][c]);
                bf16x8 k3v = *reinterpret_cast<const bf16x8*>(&k_s[kg + 147][c]);
                #pragma unroll
                for (int e = 0; e < 8; ++e) {
                    dot0 += qf[e] * bf2f_s(k0v[e]);
                    dot1 += qf[e] * bf2f_s(k1v[e]);
                    dot2 += qf[e] * bf2f_s(k2v[e]);
                    dot3 += qf[e] * bf2f_s(k3v[e]);
                }
            }
            int k;
            k = kg;       l_s[q][k] = (dot0 * inv_scale + prior[q * 196 + k]) * inv_temp;
            k = kg + 49;  l_s[q][k] = (dot1 * inv_scale + prior[q * 196 + k]) * inv_temp;
            k = kg + 98;  l_s[q][k] = (dot2 * inv_scale + prior[q * 196 + k]) * inv_temp;
            k = kg + 147; l_s[q][k] = (dot3 * inv_scale + prior[q * 196 + k]) * inv_temp;
        }
    }
    __syncthreads();

    const int lane = tid & 63;
    const int wave = tid >> 6;
    for (int q = wave; q < 52; q += 16) {
        float x0 = l_s[q][lane];
        float x1 = l_s[q][lane + 64];
        float x2 = l_s[q][lane + 128];
        float x3 = (lane < 4) ? l_s[q][lane + 192] : -1e30f;
        float m = fmaxf(fmaxf(x0, x1), fmaxf(x2, x3));
        #pragma unroll
        for (int off = 32; off > 0; off >>= 1) m = fmaxf(m, __shfl_xor(m, off));
        float e0 = expf(x0 - m), e1 = expf(x1 - m), e2 = expf(x2 - m);
        float e3 = (lane < 4) ? expf(x3 - m) : 0.0f;
        float s = e0 + e1 + e2 + e3;
        #pragma unroll
        for (int off = 32; off > 0; off >>= 1) s += __shfl_xor(s, off);
        float inv = 1.0f / s;
        float* po = attn_out + ((size_t)b * 52 + q) * 196;
        float a0 = e0 * inv, a1 = e1 * inv, a2 = e2 * inv;
        l_s[q][lane]       = a0;  po[lane]       = a0;
        l_s[q][lane + 64]  = a1;  po[lane + 64]  = a1;
        l_s[q][lane + 128] = a2;  po[lane + 128] = a2;
        if (lane < 4) { float a3 = e3 * inv; l_s[q][lane + 192] = a3; po[lane + 192] = a3; }
    }
    __syncthreads();

    if (tid < 832) {
        int q  = tid >> 4;
        int a0 = (tid & 15) * 8;
        float accv[8] = {0.f, 0.f, 0.f, 0.f, 0.f, 0.f, 0.f, 0.f};
        for (int k = 0; k < 196; ++k) {
            float wgt = l_s[q][k];
            bf16x8 vv = *reinterpret_cast<const bf16x8*>(&v_s[k][a0]);
            #pragma unroll
            for (int e = 0; e < 8; ++e) accv[e] += wgt * bf2f_s(vv[e]);
        }
        bf16x8 sv;
        #pragma unroll
        for (int e = 0; e < 8; ++e) sv[e] = (short)f2bf(accv[e]);
        *reinterpret_cast<bf16x8*>(att + ((size_t)b * 52 + q) * 128 + a0) = sv;
    }
}

// ---------------- kernel 3: output GEMM ----------------
__global__ __launch_bounds__(512)
void k_out(const unsigned short* __restrict__ att,
           const unsigned short* __restrict__ Wob,
           const float* __restrict__ bo,
           float* __restrict__ out)
{
    __shared__ unsigned short As[64][72];
    __shared__ unsigned short Bs[256][72];

    const int tid  = threadIdx.x;
    const int lane = tid & 63;
    const int wave = tid >> 6;
    const int wm   = wave >> 2;
    const int wn   = wave & 3;
    const int l15  = lane & 15;
    const int lg   = lane >> 4;
    const int row0 = blockIdx.x * 64;
    const int e0   = blockIdx.y * 256;

    f32x4 acc[2][4];
    #pragma unroll
    for (int i = 0; i < 2; ++i)
        #pragma unroll
        for (int j = 0; j < 4; ++j)
            acc[i][j] = (f32x4){0.f, 0.f, 0.f, 0.f};

    for (int ko = 0; ko < 128; ko += 64) {
        {
            int r = tid >> 3;
            int c = (tid & 7) * 8;
            bf16x8 v = *reinterpret_cast<const bf16x8*>(att + (size_t)(row0 + r) * 128 + ko + c);
            *reinterpret_cast<bf16x8*>(&As[r][c]) = v;
        }
        {
            int r = tid >> 3;
            int c = (tid & 7) * 8;
            #pragma unroll
            for (int it = 0; it < 4; ++it) {
                bf16x8 v = *reinterpret_cast<const bf16x8*>(Wob + (size_t)(e0 + it * 64 + r) * 128 + ko + c);
                *reinterpret_cast<bf16x8*>(&Bs[it * 64 + r][c]) = v;
            }
        }
        __syncthreads();
        #pragma unroll
        for (int kk = 0; kk < 2; ++kk) {
            bf16x8 af[2], bfr[4];
            #pragma unroll
            for (int mi = 0; mi < 2; ++mi)
                af[mi] = *reinterpret_cast<const bf16x8*>(&As[wm * 32 + mi * 16 + l15][kk * 32 + lg * 8]);
            #pragma unroll
            for (int ni = 0; ni < 4; ++ni)
                bfr[ni] = *reinterpret_cast<const bf16x8*>(&Bs[wn * 64 + ni * 16 + l15][kk * 32 + lg * 8]);
            #pragma unroll
            for (int mi = 0; mi < 2; ++mi)
                #pragma unroll
                for (int ni = 0; ni < 4; ++ni)
                    acc[mi][ni] = __builtin_amdgcn_mfma_f32_16x16x32_bf16(af[mi], bfr[ni], acc[mi][ni], 0, 0, 0);
        }
        __syncthreads();
    }
    #pragma unroll
    for (int mi = 0; mi < 2; ++mi) {
        #pragma unroll
        for (int i = 0; i < 4; ++i) {
            int m = row0 + wm * 32 + mi * 16 + lg * 4 + i;
            #pragma unroll
            for (int ni = 0; ni < 4; ++ni) {
                int e = e0 + wn * 64 + ni * 16 + l15;
                out[(size_t)m * 1024 + e] = acc[mi][ni][i] + bo[e];
            }
        }
    }
}

extern "C" void kernel_launch(void* const* d_in, const int* in_sizes, int n_in,
                              void* d_out, int out_size, void* d_ws, size_t ws_size,
                              hipStream_t stream)
{
    const float* patches     = (const float*)d_in[0];   // [256][196][1024]
    const float* queries     = (const float*)d_in[1];   // [52][128]
    const float* Wk          = (const float*)d_in[2];   // [128][1024]
    const float* Wv          = (const float*)d_in[3];   // [128][1024]
    const float* Wo          = (const float*)d_in[4];   // [1024][128]
    const float* bo          = (const float*)d_in[5];   // [1024]
    const float* patch_pos   = (const float*)d_in[6];   // [196][128]
    const float* temperature = (const float*)d_in[7];   // [1]
    const float* prior       = (const float*)d_in[8];   // [52][196]

    float* out      = (float*)d_out;                    // [256*52][1024]
    float* attn_out = out + (size_t)256 * 52 * 1024;    // [256*52][196]

    unsigned short* Wkvb = (unsigned short*)d_ws;              // 256*1024
    unsigned short* Wob  = Wkvb + 262144;                      // 1024*128
    unsigned short* kv   = Wob + 131072;                       // 50176*256
    unsigned short* att  = kv + (size_t)50176 * 256;           // 13312*128

    k_convert <<<128, 256, 0, stream>>>(Wk, Wv, Wo, Wkvb, Wob);
    k_keysvals<<<256, 1024, 0, stream>>>(patches, Wkvb, patch_pos, kv);
    k_attn    <<<256, 1024, 0, stream>>>(kv, queries, prior, temperature, attn_out, att);
    k_out     <<<dim3(208, 4), 512, 0, stream>>>(att, Wob, bo, out);
}